// Round 23
// baseline (98.306 us; speedup 1.0000x reference)
//
#include <hip/hip_runtime.h>
#include <hip/hip_bf16.h>

#define NUM_ENT 50000
#define NUM_REL 500
#define DIM 128
#define BQ 1024
#define KN 32
#define TBL 729          // dt in [-364, 364]
#define NTILE 512        // entities per score block (r23: 2KB span/row)
#define XPW 132          // padded words per q-row in wave-private transpose slice

typedef _Float16 f16x8 __attribute__((ext_vector_type(8)));
typedef _Float16 f16x4 __attribute__((ext_vector_type(4)));
typedef float f32x4 __attribute__((ext_vector_type(4)));

// ---------------- Kernel A: fold weights + cos table (verbatim r22 -- won) -----
__global__ void prep_kernel(const float* __restrict__ gcn_w_w,
                            const float* __restrict__ gcn_w_b,
                            const float* __restrict__ proj_w,
                            const float* __restrict__ proj_b,
                            const float* __restrict__ phase,
                            const float* __restrict__ basis_freq,
                            float* __restrict__ W,
                            float* __restrict__ bias,
                            float* __restrict__ Call,
                            float* __restrict__ COS) {
    int j = blockIdx.x;
    int d = threadIdx.x;
    if (j < 256) {
        float acc = 0.f;
        #pragma unroll 8
        for (int f = 0; f < DIM; ++f)
            acc += gcn_w_w[d * 256 + f] * proj_w[f * 256 + j];
        W[j * DIM + d] = acc;
    } else if (j < 384) {
        W[j * DIM + d] = gcn_w_w[d * 256 + 128 + (j - 256)];
    } else if (j == 384) {
        float b1 = 0.f;
        #pragma unroll 8
        for (int f = 0; f < DIM; ++f) b1 += proj_b[f] * gcn_w_w[d * 256 + f];
        bias[d] = b1 + gcn_w_b[d];
        float cc = 0.f;
        #pragma unroll 8
        for (int g = 0; g < DIM; ++g) cc += cosf(phase[g]) * proj_w[d * 256 + 128 + g];
        Call[d] = cc + proj_b[d];
    } else {
        int row = j - 385;                 // 0..728
        COS[row * DIM + d] = cosf((float)(row - 364) * basis_freq[d] + phase[d]);
    }
}

// ---------------- Kernel C: query, 512 threads (verbatim r20/r22 -- best) ------
__global__ __launch_bounds__(512) void query_kernel(const int* __restrict__ rel_idx,
                             const int* __restrict__ ts,
                             const int* __restrict__ ngh_node,
                             const int* __restrict__ ngh_eidx,
                             const int* __restrict__ ngh_ts,
                             const float* __restrict__ symbol_emb,
                             const float* __restrict__ proj_w,
                             const float* __restrict__ W,
                             const float* __restrict__ bias,
                             const float* __restrict__ Call,
                             const float* __restrict__ COS,
                             float* __restrict__ cOut,
                             _Float16* __restrict__ uOut) {
    int b = blockIdx.x;
    int t = threadIdx.x;          // 0..511
    __shared__ int sE[KN], sR[KN], sT[KN];
    __shared__ float sP[3][16][DIM];    // 24 KB partials
    __shared__ float sAgg[3 * DIM];     // 1.5 KB
    __shared__ float sAcc[4][DIM];      // 2 KB
    __shared__ float sQ[DIM];
    __shared__ float sU[4][DIM];        // 2 KB
    __shared__ float sC[2];

    if (t < KN) {
        sE[t] = ngh_node[b * KN + t];
        sR[t] = ngh_eidx[b * KN + t];
        int dt = ngh_ts[b * KN + t] - ts[b] + 364;
        sT[t] = dt < 0 ? 0 : (dt > 728 ? 728 : dt);
    }
    __syncthreads();   // B1

    int c = t & 31;
    int g = t >> 5;    // 0..15
    f32x4 pN = {0.f,0.f,0.f,0.f}, pC = pN, pR = pN;
    #pragma unroll
    for (int i = 0; i < 2; ++i) {
        int k = i * 16 + g;
        int e = sE[k];
        bool valid = (e >= 0);
        int es = valid ? e : 0;
        f32x4 vN = *reinterpret_cast<const f32x4*>(symbol_emb + (size_t)es * DIM + c * 4);
        f32x4 vC = *reinterpret_cast<const f32x4*>(COS + sT[k] * DIM + c * 4);
        f32x4 vR = *reinterpret_cast<const f32x4*>(symbol_emb + (size_t)(NUM_ENT + sR[k]) * DIM + c * 4);
        if (valid) { pN += vN; pC += vC; pR += vR; }
    }
    *reinterpret_cast<f32x4*>(&sP[0][g][c * 4]) = pN;
    *reinterpret_cast<f32x4*>(&sP[1][g][c * 4]) = pC;
    *reinterpret_cast<f32x4*>(&sP[2][g][c * 4]) = pR;

    int cnt = 0;
    #pragma unroll
    for (int k = 0; k < KN; ++k) cnt += (sE[k] >= 0) ? 1 : 0;
    __syncthreads();   // B2

    if (t < 384) {
        float s = 0.f;
        #pragma unroll
        for (int gg = 0; gg < 16; ++gg) s += sP[t >> 7][gg][t & 127];
        sAgg[t] = s;
    }
    __syncthreads();   // B3

    int d = t & 127;
    int h = t >> 7;    // 0..3
    int j0 = h * 32;
    float acc = 0.f;
    #pragma unroll
    for (int arr = 0; arr < 3; ++arr) {
        #pragma unroll 8
        for (int j = 0; j < 32; ++j) {
            int o = arr * 128 + j0 + j;
            acc += sAgg[o] * W[o * DIM + d];
        }
    }
    sAcc[h][d] = acc;
    __syncthreads();   // B4

    if (h == 0) {
        float total = sAcc[0][d] + sAcc[1][d] + sAcc[2][d] + sAcc[3][d]
                    + (float)cnt * bias[d];
        float denom = (float)(cnt > 0 ? cnt : 1);
        float sub = tanhf(total / denom);
        sQ[d] = sub * symbol_emb[(size_t)(NUM_ENT + rel_idx[b]) * DIM + d];
    }
    __syncthreads();   // B5

    float u = 0.f;
    #pragma unroll 8
    for (int dd = 0; dd < 32; ++dd)
        u += sQ[j0 + dd] * proj_w[(j0 + dd) * 256 + d];
    sU[h][d] = u;

    float cp = (t < 128) ? sQ[t] * Call[t] : 0.f;
    #pragma unroll
    for (int m = 1; m < 64; m <<= 1) cp += __shfl_xor(cp, m, 64);
    if (t == 0) sC[0] = cp;
    if (t == 64) sC[1] = cp;
    __syncthreads();   // B6

    if (h == 0)
        uOut[(size_t)b * DIM + d] =
            (_Float16)(sU[0][d] + sU[1][d] + sU[2][d] + sU[3][d]);
    if (t == 0) cOut[b] = sC[0] + sC[1];
}

// ---------------- Kernel D: score, NTILE=512 (2KB contiguous per row) ----------
// ONE mechanism vs r22: tile widened to 512 entities so each block writes 2KB
// contiguous per output row (vs 1KB) -- halves the distinct row-fragments the
// write path interleaves and doubles L2 dirty-run length (feeds the r14
// aggregation win). 4-phase staging into the same 32KB buffer: wave p pins
// 128 rows (32 f16x8 frags) after phase p. Grid unchanged: 784 = 98 tiles x
// 8 qchunks of 128 q. Per-qg: 32 MFMA; xp padded to 132 words/row; stores
// 2 rows x 1KB per instruction. Known cost: ~160 frag VGPRs -> 2 blocks/CU
// (r8 ran at 2 and won; LDS 33.8KB).
__global__ __launch_bounds__(256) void score_kernel(const _Float16* __restrict__ U,
                                                    const float* __restrict__ S,
                                                    const float* __restrict__ cArr,
                                                    float* __restrict__ out) {
    __shared__ char smem[33792];               // staging 32KB; xp 4 x 8448B
    int wgid = blockIdx.x;
    int swz = (wgid & 7) * 98 + (wgid >> 3);    // bijective, 784 = 8*98
    int xtile = swz >> 3;          // 0..97   (tile-major)
    int qchunk = swz & 7;          // 0..7
    int n0 = xtile * NTILE;

    int t = threadIdx.x;
    int lane = t & 63;
    int wave = t >> 6;
    int lr = lane & 15;
    int lg = lane >> 4;            // 0..3
    int lk = lg * 8;               // k offset within 32

    f16x8 a[8][4];

    // ---- 4-phase staging: phase p stages rows p*128..p*128+127; wave p pins --
    #pragma unroll
    for (int p = 0; p < 4; ++p) {
        const float* src = S + (size_t)(n0 + p * 128) * DIM;
        #pragma unroll 4
        for (int i = 0; i < 16; ++i) {
            int fi = i * 256 + t;                  // 0..4095
            float4 v = *reinterpret_cast<const float4*>(src + (size_t)fi * 4);
            int r = fi >> 5;                       // row 0..127
            int k8 = (fi & 31) * 8;                // byte col 0..248
            f16x4 o;
            o[0] = (_Float16)v.x; o[1] = (_Float16)v.y;
            o[2] = (_Float16)v.z; o[3] = (_Float16)v.w;
            int byte = (r * 256 + k8) ^ ((r & 7) << 4);   // XOR swizzle (write)
            *reinterpret_cast<f16x4*>(smem + byte) = o;
        }
        __syncthreads();
        if (wave == p) {
            #pragma unroll
            for (int nn = 0; nn < 8; ++nn) {
                int r = nn * 16 + lr;              // LDS row 0..127
                int rowbase = r * 256;
                int sw = (r & 7) << 4;
                #pragma unroll
                for (int kk = 0; kk < 4; ++kk) {
                    int byte = (rowbase + (kk * 32 + lk) * 2) ^ sw;
                    a[nn][kk] = *reinterpret_cast<const f16x8*>(smem + byte);
                }
            }
        }
        __syncthreads();
    }
    // tile dead; xp slices may now be written

    // wave-private transpose slice (8448B per wave)
    float* xp = reinterpret_cast<float*>(smem + wave * 8448);

    int qbase = qchunk * 128;
    for (int qg = 0; qg < 8; ++qg) {
        int q0 = qbase + qg * 16;
        f16x8 bfr[4];
        #pragma unroll
        for (int kk = 0; kk < 4; ++kk)
            bfr[kk] = *reinterpret_cast<const f16x8*>(U + (q0 + lr) * DIM + kk * 32 + lk);
        float cv = cArr[q0 + lr];

        f32x4 acc[8];
        #pragma unroll
        for (int nn = 0; nn < 8; ++nn) acc[nn] = (f32x4){0.f, 0.f, 0.f, 0.f};

        #pragma unroll
        for (int kk = 0; kk < 4; ++kk)
            #pragma unroll
            for (int nn = 0; nn < 8; ++nn)
                acc[nn] = __builtin_amdgcn_mfma_f32_16x16x32_f16(a[nn][kk], bfr[kk], acc[nn], 0, 0, 0);

        // wave-private transpose: xp[q=lr][eloc = nn*16 + lg*4 + j]
        #pragma unroll
        for (int nn = 0; nn < 8; ++nn) {
            f32x4 v = acc[nn] + cv;
            *reinterpret_cast<f32x4*>(&xp[lr * XPW + nn * 16 + lg * 4]) = v;
        }

        // stores: iter j covers 2 q-rows; per row the wave writes 512B of its
        // 128-entity slice -> block total 2KB contiguous per row
        #pragma unroll
        for (int j = 0; j < 8; ++j) {
            int row = j * 2 + (lane >> 5);
            int q = q0 + row;
            int e = n0 + wave * 128 + (lane & 31) * 4;
            if (e < NUM_ENT) {
                f32x4 v = *reinterpret_cast<const f32x4*>(&xp[row * XPW + (lane & 31) * 4]);
                *reinterpret_cast<f32x4*>(out + (size_t)q * NUM_ENT + e) = v;
            }
        }
    }
}

extern "C" void kernel_launch(void* const* d_in, const int* in_sizes, int n_in,
                              void* d_out, int out_size, void* d_ws, size_t ws_size,
                              hipStream_t stream) {
    const int*   rel_idx    = (const int*)d_in[1];
    const int*   ts         = (const int*)d_in[2];
    const int*   ngh_node   = (const int*)d_in[3];
    const int*   ngh_eidx   = (const int*)d_in[4];
    const int*   ngh_ts     = (const int*)d_in[5];
    const float* symbol_emb = (const float*)d_in[6];
    const float* gcn_w_w    = (const float*)d_in[7];
    const float* gcn_w_b    = (const float*)d_in[8];
    const float* proj_w     = (const float*)d_in[9];
    const float* proj_b     = (const float*)d_in[10];
    const float* basis_freq = (const float*)d_in[11];
    const float* phase      = (const float*)d_in[12];
    float* out = (float*)d_out;

    char* ws = (char*)d_ws;
    float*     W    = (float*)(ws + 0);          // 384*128*4 = 196608
    float*     bias = (float*)(ws + 196608);     // 512
    float*     Call = (float*)(ws + 197120);     // 512
    float*     COS  = (float*)(ws + 197632);     // 729*128*4 = 373248
    float*     cArr = (float*)(ws + 570880);     // 1024*4 = 4096
    _Float16*  U    = (_Float16*)(ws + 574976);  // 1024*128*2 = 262144

    prep_kernel<<<385 + TBL, 128, 0, stream>>>(gcn_w_w, gcn_w_b, proj_w, proj_b,
                                               phase, basis_freq, W, bias, Call, COS);
    query_kernel<<<BQ, 512, 0, stream>>>(rel_idx, ts, ngh_node, ngh_eidx, ngh_ts,
                                         symbol_emb, proj_w, W, bias, Call, COS,
                                         cArr, U);
    score_kernel<<<784, 256, 0, stream>>>(U, symbol_emb, cArr, out);
}

// Round 24
// 85.477 us; speedup vs baseline: 1.1501x; 1.1501x over previous
//
#include <hip/hip_runtime.h>
#include <hip/hip_bf16.h>

#define NUM_ENT 50000
#define NUM_REL 500
#define DIM 128
#define BQ 1024
#define KN 32
#define TBL 729          // dt in [-364, 364]
#define NTILE 256        // entities per score block
#define XPW 68           // words per q-row in wave-private transpose slice

typedef _Float16 f16x8 __attribute__((ext_vector_type(8)));
typedef _Float16 f16x4 __attribute__((ext_vector_type(4)));
typedef float f32x4 __attribute__((ext_vector_type(4)));

// ---------------- Kernel A: fold weights + cos table (verbatim r22 -- best) ----
__global__ void prep_kernel(const float* __restrict__ gcn_w_w,
                            const float* __restrict__ gcn_w_b,
                            const float* __restrict__ proj_w,
                            const float* __restrict__ proj_b,
                            const float* __restrict__ phase,
                            const float* __restrict__ basis_freq,
                            float* __restrict__ W,
                            float* __restrict__ bias,
                            float* __restrict__ Call,
                            float* __restrict__ COS) {
    int j = blockIdx.x;
    int d = threadIdx.x;
    if (j < 256) {
        float acc = 0.f;
        #pragma unroll 8
        for (int f = 0; f < DIM; ++f)
            acc += gcn_w_w[d * 256 + f] * proj_w[f * 256 + j];
        W[j * DIM + d] = acc;
    } else if (j < 384) {
        W[j * DIM + d] = gcn_w_w[d * 256 + 128 + (j - 256)];
    } else if (j == 384) {
        float b1 = 0.f;
        #pragma unroll 8
        for (int f = 0; f < DIM; ++f) b1 += proj_b[f] * gcn_w_w[d * 256 + f];
        bias[d] = b1 + gcn_w_b[d];
        float cc = 0.f;
        #pragma unroll 8
        for (int g = 0; g < DIM; ++g) cc += cosf(phase[g]) * proj_w[d * 256 + 128 + g];
        Call[d] = cc + proj_b[d];
    } else {
        int row = j - 385;                 // 0..728
        COS[row * DIM + d] = cosf((float)(row - 364) * basis_freq[d] + phase[d]);
    }
}

// ---------------- Kernel C: query, 512 threads (verbatim r20/r22 -- best) ------
__global__ __launch_bounds__(512) void query_kernel(const int* __restrict__ rel_idx,
                             const int* __restrict__ ts,
                             const int* __restrict__ ngh_node,
                             const int* __restrict__ ngh_eidx,
                             const int* __restrict__ ngh_ts,
                             const float* __restrict__ symbol_emb,
                             const float* __restrict__ proj_w,
                             const float* __restrict__ W,
                             const float* __restrict__ bias,
                             const float* __restrict__ Call,
                             const float* __restrict__ COS,
                             float* __restrict__ cOut,
                             _Float16* __restrict__ uOut) {
    int b = blockIdx.x;
    int t = threadIdx.x;          // 0..511
    __shared__ int sE[KN], sR[KN], sT[KN];
    __shared__ float sP[3][16][DIM];    // 24 KB partials
    __shared__ float sAgg[3 * DIM];     // 1.5 KB
    __shared__ float sAcc[4][DIM];      // 2 KB
    __shared__ float sQ[DIM];
    __shared__ float sU[4][DIM];        // 2 KB
    __shared__ float sC[2];

    if (t < KN) {
        sE[t] = ngh_node[b * KN + t];
        sR[t] = ngh_eidx[b * KN + t];
        int dt = ngh_ts[b * KN + t] - ts[b] + 364;
        sT[t] = dt < 0 ? 0 : (dt > 728 ? 728 : dt);
    }
    __syncthreads();   // B1

    int c = t & 31;
    int g = t >> 5;    // 0..15
    f32x4 pN = {0.f,0.f,0.f,0.f}, pC = pN, pR = pN;
    #pragma unroll
    for (int i = 0; i < 2; ++i) {
        int k = i * 16 + g;
        int e = sE[k];
        bool valid = (e >= 0);
        int es = valid ? e : 0;
        f32x4 vN = *reinterpret_cast<const f32x4*>(symbol_emb + (size_t)es * DIM + c * 4);
        f32x4 vC = *reinterpret_cast<const f32x4*>(COS + sT[k] * DIM + c * 4);
        f32x4 vR = *reinterpret_cast<const f32x4*>(symbol_emb + (size_t)(NUM_ENT + sR[k]) * DIM + c * 4);
        if (valid) { pN += vN; pC += vC; pR += vR; }
    }
    *reinterpret_cast<f32x4*>(&sP[0][g][c * 4]) = pN;
    *reinterpret_cast<f32x4*>(&sP[1][g][c * 4]) = pC;
    *reinterpret_cast<f32x4*>(&sP[2][g][c * 4]) = pR;

    int cnt = 0;
    #pragma unroll
    for (int k = 0; k < KN; ++k) cnt += (sE[k] >= 0) ? 1 : 0;
    __syncthreads();   // B2

    if (t < 384) {
        float s = 0.f;
        #pragma unroll
        for (int gg = 0; gg < 16; ++gg) s += sP[t >> 7][gg][t & 127];
        sAgg[t] = s;
    }
    __syncthreads();   // B3

    int d = t & 127;
    int h = t >> 7;    // 0..3
    int j0 = h * 32;
    float acc = 0.f;
    #pragma unroll
    for (int arr = 0; arr < 3; ++arr) {
        #pragma unroll 8
        for (int j = 0; j < 32; ++j) {
            int o = arr * 128 + j0 + j;
            acc += sAgg[o] * W[o * DIM + d];
        }
    }
    sAcc[h][d] = acc;
    __syncthreads();   // B4

    if (h == 0) {
        float total = sAcc[0][d] + sAcc[1][d] + sAcc[2][d] + sAcc[3][d]
                    + (float)cnt * bias[d];
        float denom = (float)(cnt > 0 ? cnt : 1);
        float sub = tanhf(total / denom);
        sQ[d] = sub * symbol_emb[(size_t)(NUM_ENT + rel_idx[b]) * DIM + d];
    }
    __syncthreads();   // B5

    float u = 0.f;
    #pragma unroll 8
    for (int dd = 0; dd < 32; ++dd)
        u += sQ[j0 + dd] * proj_w[(j0 + dd) * 256 + d];
    sU[h][d] = u;

    float cp = (t < 128) ? sQ[t] * Call[t] : 0.f;
    #pragma unroll
    for (int m = 1; m < 64; m <<= 1) cp += __shfl_xor(cp, m, 64);
    if (t == 0) sC[0] = cp;
    if (t == 64) sC[1] = cp;
    __syncthreads();   // B6

    if (h == 0)
        uOut[(size_t)b * DIM + d] =
            (_Float16)(sU[0][d] + sU[1][d] + sU[2][d] + sU[3][d]);
    if (t == 0) cOut[b] = sC[0] + sC[1];
}

// ---------------- Kernel D: score (VERBATIM r14/r20/r22 -- best, 784 grid) ------
__global__ __launch_bounds__(256) void score_kernel(const _Float16* __restrict__ U,
                                                    const float* __restrict__ S,
                                                    const float* __restrict__ cArr,
                                                    float* __restrict__ out) {
    __shared__ char smem[32768];               // 128-row f16 tile; per-wave xp alias
    int wgid = blockIdx.x;
    int swz = (wgid & 7) * 98 + (wgid >> 3);    // bijective, 784 = 8*98
    int xtile = swz >> 2;          // 0..195  (tile-major)
    int qchunk = swz & 3;          // 0..3
    int n0 = xtile * NTILE;

    int t = threadIdx.x;
    int lane = t & 63;
    int wave = t >> 6;
    int lr = lane & 15;
    int lg = lane >> 4;            // 0..3
    int lk = lg * 8;               // k offset within 32

    f16x8 a[4][4];

    // ---- phase 1: stage rows 0..127, waves 0/1 pin ----
    {
        const float* src = S + (size_t)n0 * DIM;
        #pragma unroll 4
        for (int i = 0; i < 16; ++i) {
            int fi = i * 256 + t;                  // 0..4095
            float4 v = *reinterpret_cast<const float4*>(src + (size_t)fi * 4);
            int r = fi >> 5;                       // row 0..127
            int k8 = (fi & 31) * 8;                // byte col 0..248
            f16x4 o;
            o[0] = (_Float16)v.x; o[1] = (_Float16)v.y;
            o[2] = (_Float16)v.z; o[3] = (_Float16)v.w;
            int byte = (r * 256 + k8) ^ ((r & 7) << 4);   // XOR swizzle (write)
            *reinterpret_cast<f16x4*>(smem + byte) = o;
        }
    }
    __syncthreads();
    if (wave < 2) {
        #pragma unroll
        for (int nn = 0; nn < 4; ++nn) {
            int r = wave * 64 + nn * 16 + lr;      // LDS row 0..127
            int rowbase = r * 256;
            int sw = (r & 7) << 4;
            #pragma unroll
            for (int kk = 0; kk < 4; ++kk) {
                int byte = (rowbase + (kk * 32 + lk) * 2) ^ sw;
                a[nn][kk] = *reinterpret_cast<const f16x8*>(smem + byte);
            }
        }
    }
    __syncthreads();

    // ---- phase 2: stage rows 128..255 into the same buffer, waves 2/3 pin ----
    {
        const float* src = S + (size_t)(n0 + 128) * DIM;
        #pragma unroll 4
        for (int i = 0; i < 16; ++i) {
            int fi = i * 256 + t;
            float4 v = *reinterpret_cast<const float4*>(src + (size_t)fi * 4);
            int r = fi >> 5;
            int k8 = (fi & 31) * 8;
            f16x4 o;
            o[0] = (_Float16)v.x; o[1] = (_Float16)v.y;
            o[2] = (_Float16)v.z; o[3] = (_Float16)v.w;
            int byte = (r * 256 + k8) ^ ((r & 7) << 4);
            *reinterpret_cast<f16x4*>(smem + byte) = o;
        }
    }
    __syncthreads();
    if (wave >= 2) {
        #pragma unroll
        for (int nn = 0; nn < 4; ++nn) {
            int r = (wave - 2) * 64 + nn * 16 + lr;   // LDS row 0..127
            int rowbase = r * 256;
            int sw = (r & 7) << 4;
            #pragma unroll
            for (int kk = 0; kk < 4; ++kk) {
                int byte = (rowbase + (kk * 32 + lk) * 2) ^ sw;
                a[nn][kk] = *reinterpret_cast<const f16x8*>(smem + byte);
            }
        }
    }
    __syncthreads();   // tile dead; xp slices may now be written

    // wave-private transpose slice (8KB per wave within the 32KB buffer)
    float* xp = reinterpret_cast<float*>(smem + wave * 8192);

    int qbase = qchunk * 256;
    for (int qg = 0; qg < 16; ++qg) {
        int q0 = qbase + qg * 16;
        f16x8 bfr[4];
        #pragma unroll
        for (int kk = 0; kk < 4; ++kk)
            bfr[kk] = *reinterpret_cast<const f16x8*>(U + (q0 + lr) * DIM + kk * 32 + lk);
        float cv = cArr[q0 + lr];

        f32x4 acc[4];
        #pragma unroll
        for (int nn = 0; nn < 4; ++nn) acc[nn] = (f32x4){0.f, 0.f, 0.f, 0.f};

        #pragma unroll
        for (int kk = 0; kk < 4; ++kk)
            #pragma unroll
            for (int nn = 0; nn < 4; ++nn)
                acc[nn] = __builtin_amdgcn_mfma_f32_16x16x32_f16(a[nn][kk], bfr[kk], acc[nn], 0, 0, 0);

        // wave-private transpose: xp[q=lr][eloc = nn*16 + lg*4 + j]
        #pragma unroll
        for (int nn = 0; nn < 4; ++nn) {
            f32x4 v = acc[nn] + cv;
            *reinterpret_cast<f32x4*>(&xp[lr * XPW + nn * 16 + lg * 4]) = v;
        }

        // stores: iter j covers q-rows j*4..j*4+3; 4 x 256B aligned segments
        #pragma unroll
        for (int j = 0; j < 4; ++j) {
            int row = j * 4 + (lane >> 4);
            int q = q0 + row;
            int e = n0 + wave * 64 + (lane & 15) * 4;
            if (e < NUM_ENT) {
                f32x4 v = *reinterpret_cast<const f32x4*>(&xp[row * XPW + (lane & 15) * 4]);
                *reinterpret_cast<f32x4*>(out + (size_t)q * NUM_ENT + e) = v;
            }
        }
    }
}

extern "C" void kernel_launch(void* const* d_in, const int* in_sizes, int n_in,
                              void* d_out, int out_size, void* d_ws, size_t ws_size,
                              hipStream_t stream) {
    const int*   rel_idx    = (const int*)d_in[1];
    const int*   ts         = (const int*)d_in[2];
    const int*   ngh_node   = (const int*)d_in[3];
    const int*   ngh_eidx   = (const int*)d_in[4];
    const int*   ngh_ts     = (const int*)d_in[5];
    const float* symbol_emb = (const float*)d_in[6];
    const float* gcn_w_w    = (const float*)d_in[7];
    const float* gcn_w_b    = (const float*)d_in[8];
    const float* proj_w     = (const float*)d_in[9];
    const float* proj_b     = (const float*)d_in[10];
    const float* basis_freq = (const float*)d_in[11];
    const float* phase      = (const float*)d_in[12];
    float* out = (float*)d_out;

    char* ws = (char*)d_ws;
    float*     W    = (float*)(ws + 0);          // 384*128*4 = 196608
    float*     bias = (float*)(ws + 196608);     // 512
    float*     Call = (float*)(ws + 197120);     // 512
    float*     COS  = (float*)(ws + 197632);     // 729*128*4 = 373248
    float*     cArr = (float*)(ws + 570880);     // 1024*4 = 4096
    _Float16*  U    = (_Float16*)(ws + 574976);  // 1024*128*2 = 262144

    prep_kernel<<<385 + TBL, 128, 0, stream>>>(gcn_w_w, gcn_w_b, proj_w, proj_b,
                                               phase, basis_freq, W, bias, Call, COS);
    query_kernel<<<BQ, 512, 0, stream>>>(rel_idx, ts, ngh_node, ngh_eidx, ngh_ts,
                                         symbol_emb, proj_w, W, bias, Call, COS,
                                         cArr, U);
    score_kernel<<<784, 256, 0, stream>>>(U, symbol_emb, cArr, out);
}